// Round 11
// baseline (1525.884 us; speedup 1.0000x reference)
//
#include <hip/hip_runtime.h>
#include <hip/hip_bf16.h>

using short8 = __attribute__((ext_vector_type(8))) short;
using short4v = __attribute__((ext_vector_type(4))) short;
using f32x4 = __attribute__((ext_vector_type(4))) float;

#define MFMA(a, b, c) __builtin_amdgcn_mfma_f32_16x16x32_bf16((a), (b), (c), 0, 0, 0)

// Wave-private design: block = 4 waves = 1 window; wave handles heads {2wv, 2wv+1}
// sequentially, fully private (no cross-wave deps until proj). LDS per wave (12KB):
//   [W+0,    W+4096)  q  [64 tok][32 dim] bf16, 64B rows, swz SWQ(tok)
//   [W+4096, W+8192)  k  same layout
//   [W+0,    W+8192)  P  [64 qtok][64 ktok] bf16, 128B rows, swz SWP (overlays q+k after S)
//   [W+8192, W+12288) vt [32 dim][64 tok] bf16, 128B rows, swz SWV(dim)
// ob [64][256] bf16 (32KB, swz SWO) overlays wave regions after B1.
// Total 49152 B -> 3 blocks/CU at VGPR<=170: __launch_bounds__(256,3)
// (empirical cap law: VGPR = 131072/(threads*arg): (512,2)->128, (512,4)->64).
#define WREG 12288
#define LDSBYTES 49152

__global__ void prep_weights(const float* __restrict__ qkv_w, const float* __restrict__ proj_w,
                             __hip_bfloat16* __restrict__ wq_t, __hip_bfloat16* __restrict__ wp_t) {
    int j = blockIdx.x, t = threadIdx.x;
    if (j < 768) {
        wq_t[j * 256 + t] = __float2bfloat16(qkv_w[t * 768 + j]);
    } else {
        int j2 = j - 768;
        wp_t[j2 * 256 + t] = __float2bfloat16(proj_w[t * 256 + j2]);
    }
}

__device__ __forceinline__ unsigned pack_bf16(float a, float b) {
    __hip_bfloat16 lo = __float2bfloat16(a), hi = __float2bfloat16(b);
    return (unsigned)*reinterpret_cast<unsigned short*>(&lo) |
           ((unsigned)*reinterpret_cast<unsigned short*>(&hi) << 16);
}

__global__ __launch_bounds__(256, 3) void swin_fused(
    const float* __restrict__ x, const float* __restrict__ mask,
    const float* __restrict__ qkv_b, const float* __restrict__ proj_b,
    const float* __restrict__ rpb,
    const __hip_bfloat16* __restrict__ wq_t, const __hip_bfloat16* __restrict__ wp_t,
    float* __restrict__ out)
{
    __shared__ __align__(16) char lds[LDSBYTES];

    const int tid = threadIdx.x;
    const int wv = tid >> 6;      // wave 0..3
    const int lane = tid & 63;
    const int lg = lane >> 4;     // 0..3
    const int li = lane & 15;     // 0..15
    const int b = blockIdx.x;
    const int w = b & 63;
    char* W = lds + wv * WREG;
    const float* xw = x + (size_t)b * 16384;
    const float* mw = mask + w * 4096;
    const float scale = 0.17677669529663687f; // 32^-0.5, folded into q

    // swizzles (consistent functions of the row index; 16B granule keeps b128/b64 aligned)
    const int swq_rd = ((li ^ (li >> 2)) & 3) << 4;  // SWQ(tok) at tok = mt*16+li
    const int swp_rd = (li & 7) << 4;                // SWP/SWV/SWO at row = *16+li

    unsigned o1u[16];             // head-1 normalized O, packed bf16 pairs
    f32x4 o[4][2];                // PV accum (head-2's survives to ob write)

#pragma unroll 1
    for (int hi = 0; hi < 2; ++hi) {
        const int h = wv * 2 + hi;

        // ---- QKV: acc[mt][ct], A-frags direct from global x ----
        f32x4 acc[4][6];
#pragma unroll
        for (int mt = 0; mt < 4; ++mt)
#pragma unroll
            for (int ct = 0; ct < 6; ++ct) acc[mt][ct] = (f32x4)0.f;
#pragma unroll
        for (int kt = 0; kt < 8; ++kt) {
            short8 af[4];
#pragma unroll
            for (int mt = 0; mt < 4; ++mt) {
                const float* xp = xw + (mt * 16 + li) * 256 + kt * 32 + lg * 8;
                float4 a0 = *(const float4*)xp;
                float4 a1 = *(const float4*)(xp + 4);
                __hip_bfloat16 t8[8] = {__float2bfloat16(a0.x), __float2bfloat16(a0.y),
                                        __float2bfloat16(a0.z), __float2bfloat16(a0.w),
                                        __float2bfloat16(a1.x), __float2bfloat16(a1.y),
                                        __float2bfloat16(a1.z), __float2bfloat16(a1.w)};
                af[mt] = *(const short8*)t8;
            }
#pragma unroll
            for (int ct = 0; ct < 6; ++ct) {
                int wcol = (ct >> 1) * 256 + h * 32 + (ct & 1) * 16 + li;
                short8 bf = *(const short8*)(wq_t + wcol * 256 + kt * 32 + lg * 8);
#pragma unroll
                for (int mt = 0; mt < 4; ++mt) acc[mt][ct] = MFMA(af[mt], bf, acc[mt][ct]);
            }
        }
        // epilogue -> q / k / vt (wave-private, no barrier)
#pragma unroll
        for (int ct = 0; ct < 6; ++ct) {
            int sel = ct >> 1, c16 = ct & 1;
            float bias = qkv_b[sel * 256 + h * 32 + c16 * 16 + li];
            if (sel < 2) {
                char* base = W + sel * 4096;
                float sc = sel ? 1.f : scale;
                int colb = (c16 * 16 + li) * 2;
#pragma unroll
                for (int mt = 0; mt < 4; ++mt)
#pragma unroll
                    for (int r = 0; r < 4; ++r) {
                        int tok = mt * 16 + lg * 4 + r;
                        int swz = ((r ^ lg) & 3) << 4;   // SWQ(tok)
                        __hip_bfloat16 tb = __float2bfloat16((acc[mt][ct][r] + bias) * sc);
                        *(__hip_bfloat16*)(base + tok * 64 + (colb ^ swz)) = tb;
                    }
            } else {
                int d = c16 * 16 + li;
#pragma unroll
                for (int mt = 0; mt < 4; ++mt) {
                    short4v t4;
#pragma unroll
                    for (int r = 0; r < 4; ++r) {
                        __hip_bfloat16 tb = __float2bfloat16(acc[mt][ct][r] + bias);
                        t4[r] = *reinterpret_cast<short*>(&tb);
                    }
                    *(short4v*)(W + 8192 + d * 128 +
                                ((mt * 32 + lg * 8) ^ ((d & 7) << 4))) = t4;
                }
            }
        }

        // ---- S: init with mask + rel-pos bias (fp32), accumulate q.k^T via MFMA C-in ----
        f32x4 s[4][4];
#pragma unroll
        for (int nt = 0; nt < 4; ++nt) {
            int n = nt * 16 + li;
            int base_nt = 112 - (n >> 3) * 15 - (n & 7);
#pragma unroll
            for (int mt = 0; mt < 4; ++mt) {
                int mb = base_nt + (mt * 2 + (lg >> 1)) * 15 + (lg & 1) * 4;
#pragma unroll
                for (int r = 0; r < 4; ++r) {
                    int m = mt * 16 + lg * 4 + r;
                    s[mt][nt][r] = mw[m * 64 + n] + rpb[(mb + r) * 8 + h];
                }
            }
        }
        {
            short8 aq[4], bk[4];
#pragma unroll
            for (int mt = 0; mt < 4; ++mt)
                aq[mt] = *(const short8*)(W + (mt * 16 + li) * 64 + ((lg * 16) ^ swq_rd));
#pragma unroll
            for (int nt = 0; nt < 4; ++nt)
                bk[nt] = *(const short8*)(W + 4096 + (nt * 16 + li) * 64 + ((lg * 16) ^ swq_rd));
#pragma unroll
            for (int mt = 0; mt < 4; ++mt)
#pragma unroll
                for (int nt = 0; nt < 4; ++nt) s[mt][nt] = MFMA(aq[mt], bk[nt], s[mt][nt]);
        }
        // softmax over full rows (deferred normalization, rinv in regs)
        float rinv[4][4];
#pragma unroll
        for (int mt = 0; mt < 4; ++mt)
#pragma unroll
            for (int r = 0; r < 4; ++r) {
                float mx = fmaxf(fmaxf(s[mt][0][r], s[mt][1][r]),
                                 fmaxf(s[mt][2][r], s[mt][3][r]));
#pragma unroll
                for (int off = 1; off < 16; off <<= 1) mx = fmaxf(mx, __shfl_xor(mx, off));
                float sum = 0.f;
#pragma unroll
                for (int nt = 0; nt < 4; ++nt) {
                    float pv = __expf(s[mt][nt][r] - mx);
                    s[mt][nt][r] = pv;
                    sum += pv;
                }
#pragma unroll
                for (int off = 1; off < 16; off <<= 1) sum += __shfl_xor(sum, off);
                rinv[mt][r] = 1.f / sum;
            }
        // P -> LDS overlay on q+k (wave-private; program order suffices)
#pragma unroll
        for (int mt = 0; mt < 4; ++mt)
#pragma unroll
            for (int r = 0; r < 4; ++r) {
                int qtok = mt * 16 + lg * 4 + r;
                int swz = (qtok & 7) << 4;               // SWP(qtok)
#pragma unroll
                for (int nt = 0; nt < 4; ++nt) {
                    __hip_bfloat16 tb = __float2bfloat16(s[mt][nt][r]);
                    *(__hip_bfloat16*)(W + qtok * 128 + (((nt * 16 + li) * 2) ^ swz)) = tb;
                }
            }
        // ---- PV ----
#pragma unroll
        for (int mt = 0; mt < 4; ++mt)
#pragma unroll
            for (int n2 = 0; n2 < 2; ++n2) o[mt][n2] = (f32x4)0.f;
#pragma unroll
        for (int kth = 0; kth < 2; ++kth) {
            short8 pa[4], vb[2];
#pragma unroll
            for (int mt = 0; mt < 4; ++mt)
                pa[mt] = *(const short8*)(W + (mt * 16 + li) * 128 +
                                          ((kth * 64 + lg * 16) ^ swp_rd));
#pragma unroll
            for (int n2 = 0; n2 < 2; ++n2)
                vb[n2] = *(const short8*)(W + 8192 + (n2 * 16 + li) * 128 +
                                          ((kth * 64 + lg * 16) ^ swp_rd));
#pragma unroll
            for (int mt = 0; mt < 4; ++mt)
#pragma unroll
                for (int n2 = 0; n2 < 2; ++n2) o[mt][n2] = MFMA(pa[mt], vb[n2], o[mt][n2]);
        }
#pragma unroll
        for (int mt = 0; mt < 4; ++mt)
#pragma unroll
            for (int n2 = 0; n2 < 2; ++n2)
#pragma unroll
                for (int r = 0; r < 4; ++r) o[mt][n2][r] *= rinv[mt][r];

        if (hi == 0) { // park head-1 O packed (16 u32, static indices)
#pragma unroll
            for (int mt = 0; mt < 4; ++mt)
#pragma unroll
                for (int n2 = 0; n2 < 2; ++n2)
#pragma unroll
                    for (int rp = 0; rp < 2; ++rp)
                        o1u[mt * 4 + n2 * 2 + rp] =
                            pack_bf16(o[mt][n2][2 * rp], o[mt][n2][2 * rp + 1]);
        }
    }

    __syncthreads(); // B1: all waves' transposer use done -> ob may overlay

    // ob writes: head 2wv (parked) and head 2wv+1 (fresh in o)
    {
        int col1 = ((wv * 2) * 32) * 2;      // byte col base head-1
        int col2 = ((wv * 2 + 1) * 32) * 2;  // head-2
#pragma unroll
        for (int mt = 0; mt < 4; ++mt)
#pragma unroll
            for (int n2 = 0; n2 < 2; ++n2)
#pragma unroll
                for (int r = 0; r < 4; ++r) {
                    int tok = mt * 16 + lg * 4 + r;
                    int swz = (tok & 7) << 4;            // SWO(tok)
                    int cb = (n2 * 16 + li) * 2;
                    unsigned short us = (unsigned short)
                        ((o1u[mt * 4 + n2 * 2 + (r >> 1)] >> (16 * (r & 1))) & 0xffffu);
                    *(unsigned short*)(lds + tok * 512 + ((col1 + cb) ^ swz)) = us;
                    __hip_bfloat16 tb = __float2bfloat16(o[mt][n2][r]);
                    *(__hip_bfloat16*)(lds + tok * 512 + ((col2 + cb) ^ swz)) = tb;
                }
    }
    __syncthreads(); // B2: ob ready

    // ---- proj: wave -> out cols wv*64 .. +63 ----
    {
        f32x4 po[4][4];
#pragma unroll
        for (int mt = 0; mt < 4; ++mt)
#pragma unroll
            for (int n = 0; n < 4; ++n) po[mt][n] = (f32x4)0.f;
#pragma unroll
        for (int kt = 0; kt < 8; ++kt) {
            short8 a[4];
#pragma unroll
            for (int mt = 0; mt < 4; ++mt)
                a[mt] = *(const short8*)(lds + (mt * 16 + li) * 512 +
                                         ((kt * 64 + lg * 16) ^ swp_rd));
#pragma unroll
            for (int n = 0; n < 4; ++n) {
                int col = wv * 64 + n * 16 + li;
                short8 bb = *(const short8*)(wp_t + col * 256 + kt * 32 + lg * 8);
#pragma unroll
                for (int mt = 0; mt < 4; ++mt) po[mt][n] = MFMA(a[mt], bb, po[mt][n]);
            }
        }
        float* op = out + (size_t)b * 16384;
#pragma unroll
        for (int n = 0; n < 4; ++n) {
            int col = wv * 64 + n * 16 + li;
            float pb = proj_b[col];
#pragma unroll
            for (int mt = 0; mt < 4; ++mt)
#pragma unroll
                for (int r = 0; r < 4; ++r)
                    op[(mt * 16 + lg * 4 + r) * 256 + col] = po[mt][n][r] + pb;
        }
    }
}

extern "C" void kernel_launch(void* const* d_in, const int* in_sizes, int n_in,
                              void* d_out, int out_size, void* d_ws, size_t ws_size,
                              hipStream_t stream) {
    const float* x      = (const float*)d_in[0];
    const float* mask   = (const float*)d_in[1];
    const float* qkv_w  = (const float*)d_in[2];
    const float* qkv_b  = (const float*)d_in[3];
    const float* proj_w = (const float*)d_in[4];
    const float* proj_b = (const float*)d_in[5];
    const float* rpb    = (const float*)d_in[6];

    __hip_bfloat16* wq_t = (__hip_bfloat16*)d_ws;          // [768][256] bf16
    __hip_bfloat16* wp_t = wq_t + 768 * 256;               // [256][256] bf16

    prep_weights<<<1024, 256, 0, stream>>>(qkv_w, proj_w, wq_t, wp_t);
    swin_fused<<<4096, 256, 0, stream>>>(x, mask, qkv_b, proj_b, rpb, wq_t, wp_t, (float*)d_out);
}

// Round 12
// 1187.931 us; speedup vs baseline: 1.2845x; 1.2845x over previous
//
#include <hip/hip_runtime.h>
#include <hip/hip_bf16.h>

using short8 = __attribute__((ext_vector_type(8))) short;
using short4v = __attribute__((ext_vector_type(4))) short;
using f32x4 = __attribute__((ext_vector_type(4))) float;

#define MFMA(a, b, c) __builtin_amdgcn_mfma_f32_16x16x32_bf16((a), (b), (c), 0, 0, 0)

// Wave-private design: block = 4 waves = 1 window; wave handles heads {2wv, 2wv+1}
// sequentially, fully private (no cross-wave deps until proj). LDS per wave (12KB):
//   [W+0,    W+4096)  q  [64 tok][32 dim] bf16, 64B rows, swz SWQ(tok)
//   [W+4096, W+8192)  k  same layout
//   [W+0,    W+8192)  P  [64 qtok][64 ktok] bf16, 128B rows, swz SWP (overlays q+k after S)
//   [W+8192, W+12288) vt [32 dim][64 tok] bf16, 128B rows, swz SWV(dim)
// ob [64][256] bf16 (32KB, swz SWO) overlays wave regions after B1.
// Total 49152 B -> 2 blocks/CU.
// R11 lesson: (256,3) => ~170-reg budget, allocator gave 84 VGPR and SPILLED
// ~1.3GB/dispatch each way (WRITE 1.64GB vs 268MB output). (256,2) => 256-reg
// budget, live set ~200 fits, zero spills; 2 independent blocks/CU desync and
// overlap (waves are barrier-free through the whole head loop).
#define WREG 12288
#define LDSBYTES 49152

__global__ void prep_weights(const float* __restrict__ qkv_w, const float* __restrict__ proj_w,
                             __hip_bfloat16* __restrict__ wq_t, __hip_bfloat16* __restrict__ wp_t) {
    int j = blockIdx.x, t = threadIdx.x;
    if (j < 768) {
        wq_t[j * 256 + t] = __float2bfloat16(qkv_w[t * 768 + j]);
    } else {
        int j2 = j - 768;
        wp_t[j2 * 256 + t] = __float2bfloat16(proj_w[t * 256 + j2]);
    }
}

__device__ __forceinline__ unsigned pack_bf16(float a, float b) {
    __hip_bfloat16 lo = __float2bfloat16(a), hi = __float2bfloat16(b);
    return (unsigned)*reinterpret_cast<unsigned short*>(&lo) |
           ((unsigned)*reinterpret_cast<unsigned short*>(&hi) << 16);
}

__global__ __launch_bounds__(256, 2) void swin_fused(
    const float* __restrict__ x, const float* __restrict__ mask,
    const float* __restrict__ qkv_b, const float* __restrict__ proj_b,
    const float* __restrict__ rpb,
    const __hip_bfloat16* __restrict__ wq_t, const __hip_bfloat16* __restrict__ wp_t,
    float* __restrict__ out)
{
    __shared__ __align__(16) char lds[LDSBYTES];

    const int tid = threadIdx.x;
    const int wv = tid >> 6;      // wave 0..3
    const int lane = tid & 63;
    const int lg = lane >> 4;     // 0..3
    const int li = lane & 15;     // 0..15
    const int b = blockIdx.x;
    const int w = b & 63;
    char* W = lds + wv * WREG;
    const float* xw = x + (size_t)b * 16384;
    const float* mw = mask + w * 4096;
    const float scale = 0.17677669529663687f; // 32^-0.5, folded into q

    // swizzles (consistent functions of the row index; 16B granule keeps b128/b64 aligned)
    const int swq_rd = ((li ^ (li >> 2)) & 3) << 4;  // SWQ(tok) at tok = mt*16+li
    const int swp_rd = (li & 7) << 4;                // SWP/SWV/SWO at row = *16+li

    unsigned o1u[16];             // head-1 normalized O, packed bf16 pairs
    f32x4 o[4][2];                // PV accum (head-2's survives to ob write)

#pragma unroll 1
    for (int hi = 0; hi < 2; ++hi) {
        const int h = wv * 2 + hi;

        // ---- QKV: acc[mt][ct], A-frags direct from global x ----
        f32x4 acc[4][6];
#pragma unroll
        for (int mt = 0; mt < 4; ++mt)
#pragma unroll
            for (int ct = 0; ct < 6; ++ct) acc[mt][ct] = (f32x4)0.f;
#pragma unroll
        for (int kt = 0; kt < 8; ++kt) {
            short8 af[4];
#pragma unroll
            for (int mt = 0; mt < 4; ++mt) {
                const float* xp = xw + (mt * 16 + li) * 256 + kt * 32 + lg * 8;
                float4 a0 = *(const float4*)xp;
                float4 a1 = *(const float4*)(xp + 4);
                __hip_bfloat16 t8[8] = {__float2bfloat16(a0.x), __float2bfloat16(a0.y),
                                        __float2bfloat16(a0.z), __float2bfloat16(a0.w),
                                        __float2bfloat16(a1.x), __float2bfloat16(a1.y),
                                        __float2bfloat16(a1.z), __float2bfloat16(a1.w)};
                af[mt] = *(const short8*)t8;
            }
#pragma unroll
            for (int ct = 0; ct < 6; ++ct) {
                int wcol = (ct >> 1) * 256 + h * 32 + (ct & 1) * 16 + li;
                short8 bf = *(const short8*)(wq_t + wcol * 256 + kt * 32 + lg * 8);
#pragma unroll
                for (int mt = 0; mt < 4; ++mt) acc[mt][ct] = MFMA(af[mt], bf, acc[mt][ct]);
            }
        }
        // epilogue -> q / k / vt (wave-private, no barrier)
#pragma unroll
        for (int ct = 0; ct < 6; ++ct) {
            int sel = ct >> 1, c16 = ct & 1;
            float bias = qkv_b[sel * 256 + h * 32 + c16 * 16 + li];
            if (sel < 2) {
                char* base = W + sel * 4096;
                float sc = sel ? 1.f : scale;
                int colb = (c16 * 16 + li) * 2;
#pragma unroll
                for (int mt = 0; mt < 4; ++mt)
#pragma unroll
                    for (int r = 0; r < 4; ++r) {
                        int tok = mt * 16 + lg * 4 + r;
                        int swz = ((r ^ lg) & 3) << 4;   // SWQ(tok)
                        __hip_bfloat16 tb = __float2bfloat16((acc[mt][ct][r] + bias) * sc);
                        *(__hip_bfloat16*)(base + tok * 64 + (colb ^ swz)) = tb;
                    }
            } else {
                int d = c16 * 16 + li;
#pragma unroll
                for (int mt = 0; mt < 4; ++mt) {
                    short4v t4;
#pragma unroll
                    for (int r = 0; r < 4; ++r) {
                        __hip_bfloat16 tb = __float2bfloat16(acc[mt][ct][r] + bias);
                        t4[r] = *reinterpret_cast<short*>(&tb);
                    }
                    *(short4v*)(W + 8192 + d * 128 +
                                ((mt * 32 + lg * 8) ^ ((d & 7) << 4))) = t4;
                }
            }
        }

        // ---- S: init with mask + rel-pos bias (fp32), accumulate q.k^T via MFMA C-in ----
        f32x4 s[4][4];
#pragma unroll
        for (int nt = 0; nt < 4; ++nt) {
            int n = nt * 16 + li;
            int base_nt = 112 - (n >> 3) * 15 - (n & 7);
#pragma unroll
            for (int mt = 0; mt < 4; ++mt) {
                int mb = base_nt + (mt * 2 + (lg >> 1)) * 15 + (lg & 1) * 4;
#pragma unroll
                for (int r = 0; r < 4; ++r) {
                    int m = mt * 16 + lg * 4 + r;
                    s[mt][nt][r] = mw[m * 64 + n] + rpb[(mb + r) * 8 + h];
                }
            }
        }
        {
            short8 aq[4], bk[4];
#pragma unroll
            for (int mt = 0; mt < 4; ++mt)
                aq[mt] = *(const short8*)(W + (mt * 16 + li) * 64 + ((lg * 16) ^ swq_rd));
#pragma unroll
            for (int nt = 0; nt < 4; ++nt)
                bk[nt] = *(const short8*)(W + 4096 + (nt * 16 + li) * 64 + ((lg * 16) ^ swq_rd));
#pragma unroll
            for (int mt = 0; mt < 4; ++mt)
#pragma unroll
                for (int nt = 0; nt < 4; ++nt) s[mt][nt] = MFMA(aq[mt], bk[nt], s[mt][nt]);
        }
        // softmax over full rows (deferred normalization, rinv in regs)
        float rinv[4][4];
#pragma unroll
        for (int mt = 0; mt < 4; ++mt)
#pragma unroll
            for (int r = 0; r < 4; ++r) {
                float mx = fmaxf(fmaxf(s[mt][0][r], s[mt][1][r]),
                                 fmaxf(s[mt][2][r], s[mt][3][r]));
#pragma unroll
                for (int off = 1; off < 16; off <<= 1) mx = fmaxf(mx, __shfl_xor(mx, off));
                float sum = 0.f;
#pragma unroll
                for (int nt = 0; nt < 4; ++nt) {
                    float pv = __expf(s[mt][nt][r] - mx);
                    s[mt][nt][r] = pv;
                    sum += pv;
                }
#pragma unroll
                for (int off = 1; off < 16; off <<= 1) sum += __shfl_xor(sum, off);
                rinv[mt][r] = 1.f / sum;
            }
        // P -> LDS overlay on q+k (wave-private; program order suffices)
#pragma unroll
        for (int mt = 0; mt < 4; ++mt)
#pragma unroll
            for (int r = 0; r < 4; ++r) {
                int qtok = mt * 16 + lg * 4 + r;
                int swz = (qtok & 7) << 4;               // SWP(qtok)
#pragma unroll
                for (int nt = 0; nt < 4; ++nt) {
                    __hip_bfloat16 tb = __float2bfloat16(s[mt][nt][r]);
                    *(__hip_bfloat16*)(W + qtok * 128 + (((nt * 16 + li) * 2) ^ swz)) = tb;
                }
            }
        // ---- PV ----
#pragma unroll
        for (int mt = 0; mt < 4; ++mt)
#pragma unroll
            for (int n2 = 0; n2 < 2; ++n2) o[mt][n2] = (f32x4)0.f;
#pragma unroll
        for (int kth = 0; kth < 2; ++kth) {
            short8 pa[4], vb[2];
#pragma unroll
            for (int mt = 0; mt < 4; ++mt)
                pa[mt] = *(const short8*)(W + (mt * 16 + li) * 128 +
                                          ((kth * 64 + lg * 16) ^ swp_rd));
#pragma unroll
            for (int n2 = 0; n2 < 2; ++n2)
                vb[n2] = *(const short8*)(W + 8192 + (n2 * 16 + li) * 128 +
                                          ((kth * 64 + lg * 16) ^ swp_rd));
#pragma unroll
            for (int mt = 0; mt < 4; ++mt)
#pragma unroll
                for (int n2 = 0; n2 < 2; ++n2) o[mt][n2] = MFMA(pa[mt], vb[n2], o[mt][n2]);
        }
#pragma unroll
        for (int mt = 0; mt < 4; ++mt)
#pragma unroll
            for (int n2 = 0; n2 < 2; ++n2)
#pragma unroll
                for (int r = 0; r < 4; ++r) o[mt][n2][r] *= rinv[mt][r];

        if (hi == 0) { // park head-1 O packed (16 u32, static indices)
#pragma unroll
            for (int mt = 0; mt < 4; ++mt)
#pragma unroll
                for (int n2 = 0; n2 < 2; ++n2)
#pragma unroll
                    for (int rp = 0; rp < 2; ++rp)
                        o1u[mt * 4 + n2 * 2 + rp] =
                            pack_bf16(o[mt][n2][2 * rp], o[mt][n2][2 * rp + 1]);
        }
    }

    __syncthreads(); // B1: all waves' transposer use done -> ob may overlay

    // ob writes: head 2wv (parked) and head 2wv+1 (fresh in o)
    {
        int col1 = ((wv * 2) * 32) * 2;      // byte col base head-1
        int col2 = ((wv * 2 + 1) * 32) * 2;  // head-2
#pragma unroll
        for (int mt = 0; mt < 4; ++mt)
#pragma unroll
            for (int n2 = 0; n2 < 2; ++n2)
#pragma unroll
                for (int r = 0; r < 4; ++r) {
                    int tok = mt * 16 + lg * 4 + r;
                    int swz = (tok & 7) << 4;            // SWO(tok)
                    int cb = (n2 * 16 + li) * 2;
                    unsigned short us = (unsigned short)
                        ((o1u[mt * 4 + n2 * 2 + (r >> 1)] >> (16 * (r & 1))) & 0xffffu);
                    *(unsigned short*)(lds + tok * 512 + ((col1 + cb) ^ swz)) = us;
                    __hip_bfloat16 tb = __float2bfloat16(o[mt][n2][r]);
                    *(__hip_bfloat16*)(lds + tok * 512 + ((col2 + cb) ^ swz)) = tb;
                }
    }
    __syncthreads(); // B2: ob ready

    // ---- proj: wave -> out cols wv*64 .. +63 ----
    {
        f32x4 po[4][4];
#pragma unroll
        for (int mt = 0; mt < 4; ++mt)
#pragma unroll
            for (int n = 0; n < 4; ++n) po[mt][n] = (f32x4)0.f;
#pragma unroll
        for (int kt = 0; kt < 8; ++kt) {
            short8 a[4];
#pragma unroll
            for (int mt = 0; mt < 4; ++mt)
                a[mt] = *(const short8*)(lds + (mt * 16 + li) * 512 +
                                         ((kt * 64 + lg * 16) ^ swp_rd));
#pragma unroll
            for (int n = 0; n < 4; ++n) {
                int col = wv * 64 + n * 16 + li;
                short8 bb = *(const short8*)(wp_t + col * 256 + kt * 32 + lg * 8);
#pragma unroll
                for (int mt = 0; mt < 4; ++mt) po[mt][n] = MFMA(a[mt], bb, po[mt][n]);
            }
        }
        float* op = out + (size_t)b * 16384;
#pragma unroll
        for (int n = 0; n < 4; ++n) {
            int col = wv * 64 + n * 16 + li;
            float pb = proj_b[col];
#pragma unroll
            for (int mt = 0; mt < 4; ++mt)
#pragma unroll
                for (int r = 0; r < 4; ++r)
                    op[(mt * 16 + lg * 4 + r) * 256 + col] = po[mt][n][r] + pb;
        }
    }
}

extern "C" void kernel_launch(void* const* d_in, const int* in_sizes, int n_in,
                              void* d_out, int out_size, void* d_ws, size_t ws_size,
                              hipStream_t stream) {
    const float* x      = (const float*)d_in[0];
    const float* mask   = (const float*)d_in[1];
    const float* qkv_w  = (const float*)d_in[2];
    const float* qkv_b  = (const float*)d_in[3];
    const float* proj_w = (const float*)d_in[4];
    const float* proj_b = (const float*)d_in[5];
    const float* rpb    = (const float*)d_in[6];

    __hip_bfloat16* wq_t = (__hip_bfloat16*)d_ws;          // [768][256] bf16
    __hip_bfloat16* wp_t = wq_t + 768 * 256;               // [256][256] bf16

    prep_weights<<<1024, 256, 0, stream>>>(qkv_w, proj_w, wq_t, wp_t);
    swin_fused<<<4096, 256, 0, stream>>>(x, mask, qkv_b, proj_b, rpb, wq_t, wp_t, (float*)d_out);
}

// Round 13
// 541.223 us; speedup vs baseline: 2.8193x; 2.1949x over previous
//
#include <hip/hip_runtime.h>
#include <hip/hip_bf16.h>

using short8 = __attribute__((ext_vector_type(8))) short;
using short4v = __attribute__((ext_vector_type(4))) short;
using f32x4 = __attribute__((ext_vector_type(4))) float;

#define MFMA(a, b, c) __builtin_amdgcn_mfma_f32_16x16x32_bf16((a), (b), (c), 0, 0, 0)

// R1-proven geometry (534us baseline): XP 264 / QKP 40 / VTP 72 / PP 72.
// R12 verdict: all occupancy-raising restructures (R4-R12) lost to this via
// spills or barrier chains. This round: R1 + fused S-init + setprio only.
#define XP 264       // xb / ob row stride (bf16 elems), 64 rows
#define QKP 40       // q/k row stride, 64 rows
#define VTP 72       // vt row stride, 32 rows
#define PP 72        // p row stride, 64 rows (overlays q+k region)
#define HSTRIDE 7424 // per-head elems: q 64*40=2560, k 2560, vt 32*72=2304

__global__ void prep_weights(const float* __restrict__ qkv_w, const float* __restrict__ proj_w,
                             __hip_bfloat16* __restrict__ wq_t, __hip_bfloat16* __restrict__ wp_t) {
    int j = blockIdx.x, t = threadIdx.x;
    if (j < 768) {
        wq_t[j * 256 + t] = __float2bfloat16(qkv_w[t * 768 + j]);
    } else {
        int j2 = j - 768;
        wp_t[j2 * 256 + t] = __float2bfloat16(proj_w[t * 256 + j2]);
    }
}

__global__ __launch_bounds__(512, 2) void swin_fused(
    const float* __restrict__ x, const float* __restrict__ mask,
    const float* __restrict__ qkv_b, const float* __restrict__ proj_b,
    const float* __restrict__ rpb,
    const __hip_bfloat16* __restrict__ wq_t, const __hip_bfloat16* __restrict__ wp_t,
    float* __restrict__ out)
{
    __shared__ __align__(16) __hip_bfloat16 xb[64 * XP];       // 33792 B; reused as O-buffer
    __shared__ __align__(16) __hip_bfloat16 hbuf[8 * HSTRIDE]; // 118784 B

    const int tid = threadIdx.x;
    const int h = tid >> 6;      // wave id = head
    const int lane = tid & 63;
    const int lg = lane >> 4;    // 0..3
    const int li = lane & 15;    // 0..15
    const int b = blockIdx.x;
    const int w = b & 63;        // window index for mask

    // ---- phase 1: x -> LDS (bf16) ----
    {
        const float* xp = x + (size_t)b * 16384;
#pragma unroll
        for (int it = 0; it < 8; ++it) {
            int e = (it * 512 + tid) * 4;
            int row = e >> 8, col = e & 255;
            float4 v = *(const float4*)(xp + e);
            __hip_bfloat16 tmp[4] = {__float2bfloat16(v.x), __float2bfloat16(v.y),
                                     __float2bfloat16(v.z), __float2bfloat16(v.w)};
            *(short4v*)(&xb[row * XP + col]) = *(const short4v*)tmp;
        }
    }
    __syncthreads();

    // ---- phase 2: QKV for head h (wave-private LDS output) ----
    __hip_bfloat16* qh = &hbuf[h * HSTRIDE];
    __hip_bfloat16* kh = qh + 2560;
    __hip_bfloat16* vth = qh + 5120;
    {
        f32x4 acc[4][6];
#pragma unroll
        for (int i = 0; i < 4; ++i)
#pragma unroll
            for (int j = 0; j < 6; ++j) acc[i][j] = (f32x4)0.f;
#pragma unroll
        for (int kt = 0; kt < 8; ++kt) {
            short8 a[4], bb[6];
#pragma unroll
            for (int mt = 0; mt < 4; ++mt)
                a[mt] = *(const short8*)(&xb[(mt * 16 + li) * XP + kt * 32 + lg * 8]);
#pragma unroll
            for (int nt = 0; nt < 6; ++nt) {
                int sel = nt >> 1, c16 = nt & 1;
                int wcol = sel * 256 + h * 32 + c16 * 16 + li;
                bb[nt] = *(const short8*)(wq_t + wcol * 256 + kt * 32 + lg * 8);
            }
            __builtin_amdgcn_s_setprio(1);
#pragma unroll
            for (int mt = 0; mt < 4; ++mt)
#pragma unroll
                for (int nt = 0; nt < 6; ++nt)
                    acc[mt][nt] = MFMA(a[mt], bb[nt], acc[mt][nt]);
            __builtin_amdgcn_s_setprio(0);
        }
        const float scale = 0.17677669529663687f; // 32^-0.5, folded into q
#pragma unroll
        for (int nt = 0; nt < 6; ++nt) {
            int sel = nt >> 1, c16 = nt & 1;
            int dim = c16 * 16 + li;
            float bias = qkv_b[sel * 256 + h * 32 + dim];
#pragma unroll
            for (int mt = 0; mt < 4; ++mt)
#pragma unroll
                for (int r = 0; r < 4; ++r) {
                    int tok = mt * 16 + lg * 4 + r;
                    float v = acc[mt][nt][r] + bias;
                    if (sel == 0)      qh[tok * QKP + dim] = __float2bfloat16(v * scale);
                    else if (sel == 1) kh[tok * QKP + dim] = __float2bfloat16(v);
                    else               vth[dim * VTP + tok] = __float2bfloat16(v);
                }
        }
    }
    __syncthreads(); // all xb reads done; xb may be reused as O-buffer

    // ---- phase 3/4: attention for head h ----
    f32x4 o[4][2];
    float rinv[4][4];
    {
        // S-init: mask + rel-pos bias as MFMA C-input (loads issue before MFMAs)
        f32x4 s[4][4];
        const float* mw = mask + w * 4096;
#pragma unroll
        for (int mt = 0; mt < 4; ++mt)
#pragma unroll
            for (int r = 0; r < 4; ++r) {
                int m = mt * 16 + lg * 4 + r;
                int ri = m >> 3, ci = m & 7;
#pragma unroll
                for (int nt = 0; nt < 4; ++nt) {
                    int n = nt * 16 + li;
                    int rj = n >> 3, cj = n & 7;
                    int idx = (ri - rj + 7) * 15 + (ci - cj + 7);
                    s[mt][nt][r] = rpb[idx * 8 + h] + mw[m * 64 + n];
                }
            }
        short8 aq[4], bk[4];
#pragma unroll
        for (int mt = 0; mt < 4; ++mt) aq[mt] = *(const short8*)(&qh[(mt * 16 + li) * QKP + lg * 8]);
#pragma unroll
        for (int nt = 0; nt < 4; ++nt) bk[nt] = *(const short8*)(&kh[(nt * 16 + li) * QKP + lg * 8]);
        __builtin_amdgcn_s_setprio(1);
#pragma unroll
        for (int mt = 0; mt < 4; ++mt)
#pragma unroll
            for (int nt = 0; nt < 4; ++nt) s[mt][nt] = MFMA(aq[mt], bk[nt], s[mt][nt]);
        __builtin_amdgcn_s_setprio(0);

        // softmax over n (across 4 in-lane tiles x 16 lanes), deferred normalization
#pragma unroll
        for (int mt = 0; mt < 4; ++mt)
#pragma unroll
            for (int r = 0; r < 4; ++r) {
                float mx = fmaxf(fmaxf(s[mt][0][r], s[mt][1][r]), fmaxf(s[mt][2][r], s[mt][3][r]));
#pragma unroll
                for (int off = 1; off < 16; off <<= 1) mx = fmaxf(mx, __shfl_xor(mx, off));
                float sum = 0.f;
#pragma unroll
                for (int nt = 0; nt < 4; ++nt) {
                    float p = __expf(s[mt][nt][r] - mx);
                    s[mt][nt][r] = p;
                    sum += p;
                }
#pragma unroll
                for (int off = 1; off < 16; off <<= 1) sum += __shfl_xor(sum, off);
                rinv[mt][r] = 1.f / sum;
            }
        // P -> LDS (overlay on dead q+k region; wave-private, no barrier needed)
        __hip_bfloat16* ph = qh;
#pragma unroll
        for (int mt = 0; mt < 4; ++mt)
#pragma unroll
            for (int r = 0; r < 4; ++r) {
                int m = mt * 16 + lg * 4 + r;
#pragma unroll
                for (int nt = 0; nt < 4; ++nt)
                    ph[m * PP + nt * 16 + li] = __float2bfloat16(s[mt][nt][r]);
            }
        // PV
#pragma unroll
        for (int mt = 0; mt < 4; ++mt)
#pragma unroll
            for (int nt = 0; nt < 2; ++nt) o[mt][nt] = (f32x4)0.f;
#pragma unroll
        for (int kt = 0; kt < 2; ++kt) {
            short8 pa[4], vb[2];
#pragma unroll
            for (int mt = 0; mt < 4; ++mt)
                pa[mt] = *(const short8*)(&ph[(mt * 16 + li) * PP + kt * 32 + lg * 8]);
#pragma unroll
            for (int nt = 0; nt < 2; ++nt)
                vb[nt] = *(const short8*)(&vth[(nt * 16 + li) * VTP + kt * 32 + lg * 8]);
            __builtin_amdgcn_s_setprio(1);
#pragma unroll
            for (int mt = 0; mt < 4; ++mt)
#pragma unroll
                for (int nt = 0; nt < 2; ++nt) o[mt][nt] = MFMA(pa[mt], vb[nt], o[mt][nt]);
            __builtin_amdgcn_s_setprio(0);
        }
    }
    // O (normalized) -> ob (= xb region), cols h*32..h*32+31
#pragma unroll
    for (int mt = 0; mt < 4; ++mt)
#pragma unroll
        for (int nt = 0; nt < 2; ++nt)
#pragma unroll
            for (int r = 0; r < 4; ++r) {
                int m = mt * 16 + lg * 4 + r;
                xb[m * XP + h * 32 + nt * 16 + li] = __float2bfloat16(o[mt][nt][r] * rinv[mt][r]);
            }
    __syncthreads();

    // ---- phase 5: proj; wave h -> out cols h*32..h*32+31 ----
    {
        f32x4 po[4][2];
#pragma unroll
        for (int mt = 0; mt < 4; ++mt)
#pragma unroll
            for (int nt = 0; nt < 2; ++nt) po[mt][nt] = (f32x4)0.f;
#pragma unroll
        for (int kt = 0; kt < 8; ++kt) {
            short8 a[4], bb[2];
#pragma unroll
            for (int mt = 0; mt < 4; ++mt)
                a[mt] = *(const short8*)(&xb[(mt * 16 + li) * XP + kt * 32 + lg * 8]);
#pragma unroll
            for (int nt = 0; nt < 2; ++nt) {
                int col = h * 32 + nt * 16 + li;
                bb[nt] = *(const short8*)(wp_t + col * 256 + kt * 32 + lg * 8);
            }
            __builtin_amdgcn_s_setprio(1);
#pragma unroll
            for (int mt = 0; mt < 4; ++mt)
#pragma unroll
                for (int nt = 0; nt < 2; ++nt) po[mt][nt] = MFMA(a[mt], bb[nt], po[mt][nt]);
            __builtin_amdgcn_s_setprio(0);
        }
        float* op = out + (size_t)b * 16384;
#pragma unroll
        for (int nt = 0; nt < 2; ++nt) {
            int col = h * 32 + nt * 16 + li;
            float pb = proj_b[col];
#pragma unroll
            for (int mt = 0; mt < 4; ++mt)
#pragma unroll
                for (int r = 0; r < 4; ++r) {
                    int m = mt * 16 + lg * 4 + r;
                    op[m * 256 + col] = po[mt][nt][r] + pb;
                }
        }
    }
}

extern "C" void kernel_launch(void* const* d_in, const int* in_sizes, int n_in,
                              void* d_out, int out_size, void* d_ws, size_t ws_size,
                              hipStream_t stream) {
    const float* x      = (const float*)d_in[0];
    const float* mask   = (const float*)d_in[1];
    const float* qkv_w  = (const float*)d_in[2];
    const float* qkv_b  = (const float*)d_in[3];
    const float* proj_w = (const float*)d_in[4];
    const float* proj_b = (const float*)d_in[5];
    const float* rpb    = (const float*)d_in[6];

    __hip_bfloat16* wq_t = (__hip_bfloat16*)d_ws;          // [768][256] bf16
    __hip_bfloat16* wp_t = wq_t + 768 * 256;               // [256][256] bf16

    prep_weights<<<1024, 256, 0, stream>>>(qkv_w, proj_w, wq_t, wp_t);
    swin_fused<<<4096, 512, 0, stream>>>(x, mask, qkv_b, proj_b, rpb, wq_t, wp_t, (float*)d_out);
}